// Round 2
// baseline (496.535 us; speedup 1.0000x reference)
//
#include <hip/hip_runtime.h>
#include <hip/hip_bf16.h>
#include <math.h>

#define BB 2
#define CC 256
#define NN 6272      // 8*28*28
#define NT16 392     // 16-query tiles per batch
#define NKB32 196    // 32-key tiles per batch
#define SCL 0.09016844005f   // log2(e)/sqrt(256)  (folded into Q at projection)

typedef __attribute__((ext_vector_type(8))) short s8v;   // 8 bf16 (4 VGPRs)
typedef __attribute__((ext_vector_type(4))) float f4v;   // MFMA acc / 16B vec
typedef __attribute__((ext_vector_type(4))) unsigned short us4v;  // 4 bf16

__device__ inline unsigned short f2bf(float f) {
  unsigned u = __builtin_bit_cast(unsigned, f);
  u += 0x7fffu + ((u >> 16) & 1u);     // RNE
  return (unsigned short)(u >> 16);
}

__device__ inline float bf2f(unsigned short h) {
  unsigned u = (unsigned)h << 16;
  return __builtin_bit_cast(float, u);
}

// ---------------------------------------------------------------------------
// fp32 weights -> bf16 (once per launch)
// ---------------------------------------------------------------------------
__global__ __launch_bounds__(256) void wcvt_kernel(
    const float* __restrict__ wq, const float* __restrict__ wk,
    const float* __restrict__ wv, unsigned short* __restrict__ Wb)
{
  int i = (blockIdx.x * 256 + threadIdx.x) * 4;   // grid 192 -> i < 196608
  const float* src = (i < 65536) ? wq : (i < 131072 ? wk : wv);
  int off = i & 65535;
  float4 v = *(const float4*)(src + off);
  ushort4 o;
  o.x = f2bf(v.x); o.y = f2bf(v.y); o.z = f2bf(v.z); o.w = f2bf(v.w);
  *(ushort4*)(Wb + i) = o;
}

// ---------------------------------------------------------------------------
// MFMA projection
// p=0: Q*SCL -> [B][N][C]   p=1: K -> [B][N][C]   p=2: V -> [B][C][N]
// ---------------------------------------------------------------------------
__global__ __launch_bounds__(256) void proj_kernel(
    const float* __restrict__ x, const float* __restrict__ ctx,
    const unsigned short* __restrict__ Wb,
    const float* __restrict__ bq, const float* __restrict__ bk,
    const float* __restrict__ bv,
    unsigned short* __restrict__ Q, unsigned short* __restrict__ Kk,
    unsigned short* __restrict__ V)
{
  const int p = blockIdx.z, b = blockIdx.y;
  const int n0 = blockIdx.x * 32;
  const int tid = threadIdx.x;
  const float* in = (p == 0 ? x : ctx) + (size_t)b * CC * NN;
  const unsigned short* W = Wb + (size_t)p * 65536;
  const float* bias = (p == 0 ? bq : (p == 1 ? bk : bv));

  __shared__ __align__(16) unsigned short lds[32][264];   // [n][c]
  for (int it = tid; it < 2048; it += 256) {
    int c  = it >> 3;
    int n4 = (it & 7) << 2;
    float4 v = *(const float4*)(in + (size_t)c * NN + n0 + n4);
    lds[n4 + 0][c] = f2bf(v.x);
    lds[n4 + 1][c] = f2bf(v.y);
    lds[n4 + 2][c] = f2bf(v.z);
    lds[n4 + 3][c] = f2bf(v.w);
  }
  __syncthreads();

  const int lane = tid & 63, l15 = lane & 15, g = lane >> 4;
  const int obase = (tid >> 6) * 64;

  f4v acc[4][2];
#pragma unroll
  for (int mt = 0; mt < 4; ++mt) {
    float4 b4 = *(const float4*)(bias + obase + mt * 16 + g * 4);
    f4v bi = {b4.x, b4.y, b4.z, b4.w};
    acc[mt][0] = bi; acc[mt][1] = bi;
  }

#pragma unroll
  for (int ks = 0; ks < 8; ++ks) {
    s8v bf0 = *(const s8v*)(&lds[l15][ks * 32 + g * 8]);
    s8v bf1 = *(const s8v*)(&lds[16 + l15][ks * 32 + g * 8]);
#pragma unroll
    for (int mt = 0; mt < 4; ++mt) {
      s8v wa = *(const s8v*)(W + (size_t)(obase + mt * 16 + l15) * CC + ks * 32 + g * 8);
      acc[mt][0] = __builtin_amdgcn_mfma_f32_16x16x32_bf16(wa, bf0, acc[mt][0], 0, 0, 0);
      acc[mt][1] = __builtin_amdgcn_mfma_f32_16x16x32_bf16(wa, bf1, acc[mt][1], 0, 0, 0);
    }
  }

  if (p == 0) {
#pragma unroll
    for (int mt = 0; mt < 4; ++mt)
#pragma unroll
      for (int qq = 0; qq < 2; ++qq)
#pragma unroll
        for (int r = 0; r < 4; ++r)
          acc[mt][qq][r] *= SCL;
  }

  if (p < 2) {
    unsigned short* dst = (p == 0 ? Q : Kk) + (size_t)b * NN * CC;
#pragma unroll
    for (int mt = 0; mt < 4; ++mt)
#pragma unroll
      for (int qq = 0; qq < 2; ++qq) {
        ushort4 pk;
        pk.x = f2bf(acc[mt][qq][0]); pk.y = f2bf(acc[mt][qq][1]);
        pk.z = f2bf(acc[mt][qq][2]); pk.w = f2bf(acc[mt][qq][3]);
        *(ushort4*)(dst + (size_t)(n0 + qq * 16 + l15) * CC + obase + mt * 16 + g * 4) = pk;
      }
  } else {
    unsigned short* dstb = V + (size_t)b * CC * NN;
#pragma unroll
    for (int mt = 0; mt < 4; ++mt)
#pragma unroll
      for (int qq = 0; qq < 2; ++qq)
#pragma unroll
        for (int r = 0; r < 4; ++r)
          dstb[(size_t)(obase + mt * 16 + g * 4 + r) * NN + n0 + qq * 16 + l15] =
              f2bf(acc[mt][qq][r]);
  }
}

// ---------------------------------------------------------------------------
// Flash attention (no-max exp2). 256-thread blocks = 4 waves, 16 queries/wave.
// v3: latency-bound diagnosis (all pipes <50%, 2 waves/SIMD). Raise occupancy:
// drop V staging entirely -- PV A-fragments are read straight from global
// (V is L2-resident, 3.2 MB/batch; the 4 lockstep waves share the 16 KB
// V-tile via L1/L2). LDS = K dbuf 32 KB + P 4.5 KB = 36.6 KB and the 168-reg
// footprint (96 arch + 72 acc) now fit 3 blocks/CU = 12 waves/CU
// (launch_bounds(256,3), cap 170). Staging per tile halves to 16 KB.
// split=3 -> 588 blocks <= 768 resident slots = one round, no tail round.
// ---------------------------------------------------------------------------
__global__ __launch_bounds__(256, 3) void attn_kernel(
    const unsigned short* __restrict__ Qg,
    const unsigned short* __restrict__ Kg,
    const unsigned short* __restrict__ Vg,
    unsigned short* __restrict__ Opart,  // [wid16*split+s][4096] bf16
    float* __restrict__ ml,              // [wid16*split+s][16]
    int split, int kb_base, int kb_rem)
{
  const int s     = blockIdx.x % split;
  const int stile = blockIdx.x / split;   // 0..195
  const int b     = stile / 98;
  const int qsup  = stile % 98;
  const int tid   = threadIdx.x;
  const int w     = tid >> 6;             // 0..3
  const int lane  = tid & 63;
  const int l15 = lane & 15, g = lane >> 4;
  const int qt16  = qsup * 4 + w;         // 16-query tile in batch (0..391)
  const int q0    = qt16 * 16;
  const int wid16 = b * NT16 + qt16;

  const int start = s * kb_base + (s < kb_rem ? s : kb_rem);
  const int cnt   = kb_base + (s < kb_rem ? 1 : 0);

  const unsigned short* Qb = Qg + (size_t)b * NN * CC;
  const unsigned short* Kb = Kg + (size_t)b * NN * CC;
  const unsigned short* Vb = Vg + (size_t)b * CC * NN;

  __shared__ __align__(16) unsigned short K_lds[2][32 * 256];  // 2 x 16 KB
  __shared__ __align__(16) unsigned short P_lds[4][16][36];    // per-wave P

  // ---- Q B-fragments pinned (32 VGPRs) -------------------------------
  s8v qf[8];
#pragma unroll
  for (int ks = 0; ks < 8; ++ks)
    qf[ks] = *(const s8v*)(Qb + (size_t)(q0 + l15) * CC + ks * 32 + g * 8);

  f4v ot[16];
  const f4v fz = {0.f, 0.f, 0.f, 0.f};
#pragma unroll
  for (int mt = 0; mt < 16; ++mt) ot[mt] = fz;

  float lsum = 0.f;

  // ---- async stage of one 32-key K tile (all 4 waves) ----------------
  auto stage = [&](int buf, int kb32) {
    const int kb = kb32 * 32;
#pragma unroll
    for (int i = 0; i < 4; ++i) {
      int chunk = w * 256 + i * 64 + lane;             // 0..1023 (16B units)
      int r = chunk >> 5, cc = chunk & 31;
      const unsigned short* gp =
          Kb + (size_t)(kb + r) * CC + ((cc ^ (r & 15)) << 3);
      __builtin_amdgcn_global_load_lds(
          (const __attribute__((address_space(1))) unsigned int*)gp,
          (__attribute__((address_space(3))) unsigned int*)(&K_lds[buf][chunk * 8]),
          16, 0, 0);
    }
  };

  stage(0, start);
  int cur = 0;

  for (int ib = 0; ib < cnt; ++ib) {
    __syncthreads();                       // buf[cur] staged; prev compute done
    if (ib + 1 < cnt) stage(cur ^ 1, start + ib + 1);   // prefetch next

    const unsigned short* Kl = &K_lds[cur][0];
    const int kb = (start + ib) * 32;

    // ---- S^T = K @ Q^T (32 keys x 16 queries; Q pre-scaled) ----------
    f4v st[2];
    st[0] = fz; st[1] = fz;
#pragma unroll
    for (int ks = 0; ks < 8; ++ks) {
      const int co = ((ks * 4 + g) ^ l15) << 3;        // swizzled 16B chunk
#pragma unroll
      for (int kt = 0; kt < 2; ++kt) {
        s8v ka = *(const s8v*)(Kl + (kt * 16 + l15) * 256 + co);
        st[kt] = __builtin_amdgcn_mfma_f32_16x16x32_bf16(ka, qf[ks], st[kt], 0, 0, 0);
      }
    }

    // ---- P = exp2(S), accumulate l, pack to per-wave LDS -------------
#pragma unroll
    for (int kt = 0; kt < 2; ++kt) {
      float p0 = __builtin_amdgcn_exp2f(st[kt][0]);
      float p1 = __builtin_amdgcn_exp2f(st[kt][1]);
      float p2 = __builtin_amdgcn_exp2f(st[kt][2]);
      float p3 = __builtin_amdgcn_exp2f(st[kt][3]);
      lsum += (p0 + p1) + (p2 + p3);
      ushort4 pk;
      pk.x = f2bf(p0); pk.y = f2bf(p1); pk.z = f2bf(p2); pk.w = f2bf(p3);
      *(ushort4*)(&P_lds[w][l15][kt * 16 + 4 * g]) = pk;
    }

    // ---- O^T += V^T @ P^T; V fragments straight from global (L2) -----
    s8v pb = *(const s8v*)(&P_lds[w][l15][g * 8]);
    const unsigned short* vbase = Vb + (size_t)l15 * NN + kb + g * 8;
#pragma unroll
    for (int mt = 0; mt < 16; ++mt) {
      s8v va = *(const s8v*)(vbase + (size_t)(mt * 16) * NN);
      ot[mt] = __builtin_amdgcn_mfma_f32_16x16x32_bf16(va, pb, ot[mt], 0, 0, 0);
    }

    cur ^= 1;
  }

  // ---- reduce l across the 4 g-groups --------------------------------
  lsum += __shfl_xor(lsum, 16);
  lsum += __shfl_xor(lsum, 32);

  // ---- nontemporal bf16 fragment-native partial dump -----------------
  unsigned short* Ob = Opart + (size_t)(wid16 * split + s) * 4096;
#pragma unroll
  for (int mt = 0; mt < 16; ++mt) {
    us4v o4;
    o4.x = f2bf(ot[mt][0]); o4.y = f2bf(ot[mt][1]);
    o4.z = f2bf(ot[mt][2]); o4.w = f2bf(ot[mt][3]);
    __builtin_nontemporal_store(o4, (us4v*)(Ob + mt * 256 + lane * 4));
  }

  if (lane < 16)
    ml[(size_t)(wid16 * split + s) * 16 + lane] = lsum;
}

// ---------------------------------------------------------------------------
// Merge v2: block = 2 adjacent 16-q tiles (32 n x 256 c).
// Phase 1: read Opart fragment-native (dense 8B/lane), sum over splits,
//          normalize, deposit fp32 into lds_o[c][n] (pad 33).
// Phase 2: fully-coalesced out = lds_o + x (128B line segments).
// ---------------------------------------------------------------------------
__global__ __launch_bounds__(256) void merge_kernel(
    const unsigned short* __restrict__ Opart,
    const float* __restrict__ ml,
    const float* __restrict__ x,
    float* __restrict__ out,
    int split)
{
  const int wid32 = blockIdx.x;             // 0..391
  const int b  = wid32 / (NT16 / 2);
  const int pi = wid32 % (NT16 / 2);
  const int n0 = pi * 32;
  const int tid = threadIdx.x;
  const int w = tid >> 6;
  const int lane = tid & 63;
  const int l15 = lane & 15, g = lane >> 4;

  __shared__ float lds_o[256][33];          // 33.8 KB

#pragma unroll
  for (int t = 0; t < 2; ++t) {
    const int wid16 = b * NT16 + pi * 2 + t;
    float L = 0.f;
#pragma unroll
    for (int s = 0; s < 8; ++s)
      if (s < split)
        L += ml[(size_t)(wid16 * split + s) * 16 + l15];
    const float invL = 1.f / L;

#pragma unroll
    for (int j = 0; j < 4; ++j) {
      int mt = j * 4 + w;
      float a0 = 0.f, a1 = 0.f, a2 = 0.f, a3 = 0.f;
#pragma unroll
      for (int s = 0; s < 8; ++s)
        if (s < split) {
          const us4v* Op4 = (const us4v*)(Opart + (size_t)(wid16 * split + s) * 4096);
          us4v o4 = __builtin_nontemporal_load(Op4 + mt * 64 + lane);
          a0 += bf2f(o4.x); a1 += bf2f(o4.y);
          a2 += bf2f(o4.z); a3 += bf2f(o4.w);
        }
      int c = mt * 16 + g * 4;
      int nl = t * 16 + l15;
      lds_o[c + 0][nl] = a0 * invL;
      lds_o[c + 1][nl] = a1 * invL;
      lds_o[c + 2][nl] = a2 * invL;
      lds_o[c + 3][nl] = a3 * invL;
    }
  }
  __syncthreads();

  const size_t base = (size_t)b * CC * NN + n0;
  const int n = tid & 31;
  const int c0 = tid >> 5;                  // 0..7
#pragma unroll
  for (int cg = 0; cg < 32; ++cg) {
    int c = cg * 8 + c0;
    size_t idx = base + (size_t)c * NN + n;
    out[idx] = lds_o[c][n] + x[idx];
  }
}

extern "C" void kernel_launch(void* const* d_in, const int* in_sizes, int n_in,
                              void* d_out, int out_size, void* d_ws, size_t ws_size,
                              hipStream_t stream) {
  const float* x   = (const float*)d_in[0];
  const float* ctx = (const float*)d_in[1];
  const float* wq  = (const float*)d_in[2];
  const float* bq  = (const float*)d_in[3];
  const float* wk  = (const float*)d_in[4];
  const float* bk  = (const float*)d_in[5];
  const float* wv  = (const float*)d_in[6];
  const float* bv  = (const float*)d_in[7];
  float* out = (float*)d_out;

  const size_t sz = (size_t)BB * NN * CC;
  unsigned short* Wb = (unsigned short*)d_ws;        // 384 KB
  unsigned short* Q  = Wb + 3 * 65536;
  unsigned short* K  = Q + sz;
  unsigned short* V  = K + sz;
  const size_t fixedB = 3 * 65536 * 2 + 3 * sz * 2;  // 19.66 MB

  // split=3 -> 588 blocks <= 768 resident slots (3 blocks/CU x 256 CU)
  int split = 1;
  const int cands[3] = {3, 2, 1};
  for (int i = 0; i < 3; ++i) {
    size_t need = fixedB + (size_t)cands[i] * (BB * NT16) *
                  (4096 * sizeof(unsigned short) + 16 * sizeof(float));
    if (ws_size >= need) { split = cands[i]; break; }
  }
  unsigned short* Opart = (unsigned short*)((char*)d_ws + fixedB);
  float* ml = (float*)(Opart + (size_t)split * (BB * NT16) * 4096);
  const int kb_base = NKB32 / split, kb_rem = NKB32 % split;

  wcvt_kernel<<<dim3(192), dim3(256), 0, stream>>>(wq, wk, wv, Wb);
  proj_kernel<<<dim3(NN / 32, BB, 3), dim3(256), 0, stream>>>(
      x, ctx, Wb, bq, bk, bv, Q, K, V);
  attn_kernel<<<dim3(196 * split), dim3(256), 0, stream>>>(
      Q, K, V, Opart, ml, split, kb_base, kb_rem);
  merge_kernel<<<dim3(BB * NT16 / 2), dim3(256), 0, stream>>>(
      Opart, ml, x, out, split);
}

// Round 3
// 254.266 us; speedup vs baseline: 1.9528x; 1.9528x over previous
//
#include <hip/hip_runtime.h>
#include <hip/hip_bf16.h>
#include <math.h>

#define BB 2
#define CC 256
#define NN 6272      // 8*28*28
#define NT32 196     // 32-query tiles per batch
#define NKB32 196    // 32-key tiles per batch
#define SCL 0.09016844005f   // log2(e)/sqrt(256)  (folded into Q at projection)

typedef __attribute__((ext_vector_type(8))) short s8v;   // 8 bf16 (4 VGPRs)
typedef __attribute__((ext_vector_type(4))) float f4v;   // MFMA acc / 16B vec
typedef __attribute__((ext_vector_type(4))) unsigned short us4v;  // 4 bf16

__device__ inline unsigned short f2bf(float f) {
  unsigned u = __builtin_bit_cast(unsigned, f);
  u += 0x7fffu + ((u >> 16) & 1u);     // RNE
  return (unsigned short)(u >> 16);
}

__device__ inline float bf2f(unsigned short h) {
  unsigned u = (unsigned)h << 16;
  return __builtin_bit_cast(float, u);
}

// ---------------------------------------------------------------------------
// fp32 weights -> bf16 (once per launch)
// ---------------------------------------------------------------------------
__global__ __launch_bounds__(256) void wcvt_kernel(
    const float* __restrict__ wq, const float* __restrict__ wk,
    const float* __restrict__ wv, unsigned short* __restrict__ Wb)
{
  int i = (blockIdx.x * 256 + threadIdx.x) * 4;   // grid 192 -> i < 196608
  const float* src = (i < 65536) ? wq : (i < 131072 ? wk : wv);
  int off = i & 65535;
  float4 v = *(const float4*)(src + off);
  ushort4 o;
  o.x = f2bf(v.x); o.y = f2bf(v.y); o.z = f2bf(v.z); o.w = f2bf(v.w);
  *(ushort4*)(Wb + i) = o;
}

// ---------------------------------------------------------------------------
// MFMA projection
// p=0: Q*SCL -> [B][N][C]   p=1: K -> [B][N][C]   p=2: V -> [B][C][N]
// ---------------------------------------------------------------------------
__global__ __launch_bounds__(256) void proj_kernel(
    const float* __restrict__ x, const float* __restrict__ ctx,
    const unsigned short* __restrict__ Wb,
    const float* __restrict__ bq, const float* __restrict__ bk,
    const float* __restrict__ bv,
    unsigned short* __restrict__ Q, unsigned short* __restrict__ Kk,
    unsigned short* __restrict__ V)
{
  const int p = blockIdx.z, b = blockIdx.y;
  const int n0 = blockIdx.x * 32;
  const int tid = threadIdx.x;
  const float* in = (p == 0 ? x : ctx) + (size_t)b * CC * NN;
  const unsigned short* W = Wb + (size_t)p * 65536;
  const float* bias = (p == 0 ? bq : (p == 1 ? bk : bv));

  __shared__ __align__(16) unsigned short lds[32][264];   // [n][c]
  for (int it = tid; it < 2048; it += 256) {
    int c  = it >> 3;
    int n4 = (it & 7) << 2;
    float4 v = *(const float4*)(in + (size_t)c * NN + n0 + n4);
    lds[n4 + 0][c] = f2bf(v.x);
    lds[n4 + 1][c] = f2bf(v.y);
    lds[n4 + 2][c] = f2bf(v.z);
    lds[n4 + 3][c] = f2bf(v.w);
  }
  __syncthreads();

  const int lane = tid & 63, l15 = lane & 15, g = lane >> 4;
  const int obase = (tid >> 6) * 64;

  f4v acc[4][2];
#pragma unroll
  for (int mt = 0; mt < 4; ++mt) {
    float4 b4 = *(const float4*)(bias + obase + mt * 16 + g * 4);
    f4v bi = {b4.x, b4.y, b4.z, b4.w};
    acc[mt][0] = bi; acc[mt][1] = bi;
  }

#pragma unroll
  for (int ks = 0; ks < 8; ++ks) {
    s8v bf0 = *(const s8v*)(&lds[l15][ks * 32 + g * 8]);
    s8v bf1 = *(const s8v*)(&lds[16 + l15][ks * 32 + g * 8]);
#pragma unroll
    for (int mt = 0; mt < 4; ++mt) {
      s8v wa = *(const s8v*)(W + (size_t)(obase + mt * 16 + l15) * CC + ks * 32 + g * 8);
      acc[mt][0] = __builtin_amdgcn_mfma_f32_16x16x32_bf16(wa, bf0, acc[mt][0], 0, 0, 0);
      acc[mt][1] = __builtin_amdgcn_mfma_f32_16x16x32_bf16(wa, bf1, acc[mt][1], 0, 0, 0);
    }
  }

  if (p == 0) {
#pragma unroll
    for (int mt = 0; mt < 4; ++mt)
#pragma unroll
      for (int qq = 0; qq < 2; ++qq)
#pragma unroll
        for (int r = 0; r < 4; ++r)
          acc[mt][qq][r] *= SCL;
  }

  if (p < 2) {
    unsigned short* dst = (p == 0 ? Q : Kk) + (size_t)b * NN * CC;
#pragma unroll
    for (int mt = 0; mt < 4; ++mt)
#pragma unroll
      for (int qq = 0; qq < 2; ++qq) {
        ushort4 pk;
        pk.x = f2bf(acc[mt][qq][0]); pk.y = f2bf(acc[mt][qq][1]);
        pk.z = f2bf(acc[mt][qq][2]); pk.w = f2bf(acc[mt][qq][3]);
        *(ushort4*)(dst + (size_t)(n0 + qq * 16 + l15) * CC + obase + mt * 16 + g * 4) = pk;
      }
  } else {
    unsigned short* dstb = V + (size_t)b * CC * NN;
#pragma unroll
    for (int mt = 0; mt < 4; ++mt)
#pragma unroll
      for (int qq = 0; qq < 2; ++qq)
#pragma unroll
        for (int r = 0; r < 4; ++r)
          dstb[(size_t)(obase + mt * 16 + g * 4 + r) * NN + n0 + qq * 16 + l15] =
              f2bf(acc[mt][qq][r]);
  }
}

// ---------------------------------------------------------------------------
// Flash attention (no-max exp2), wave-pair split. 256-thread blocks = 4 waves
// = 2 pairs; each pair owns 32 queries. Within a pair, wave h:
//   QK:  keys h*16..h*16+15 for all 32 q  (8 K-frag b128 reads, halved)
//   PV:  channels h*128..h*128+127, all 32 keys (8 V-frag reads, reused 2 qt)
// P (16k x 32q bf16) exchanged via per-pair LDS; the mid-tile barrier is a
// RAW s_barrier with lgkmcnt-only wait (no vmcnt drain -> staging prefetch
// survives across it; drains at the next __syncthreads). LDS traffic per
// wave-tile: 18 b128 reads + 2 b64 writes (~19 KB) vs v1's ~33 KB, same MFMA.
// Regs ~180 (qf 64 + ot 64 + st 8 + misc): no spill at 2 waves/SIMD.
// LDS 69.6 KB -> 2 blocks/CU. L partials stored per key-half (ml stride 64).
// ---------------------------------------------------------------------------
__global__ __launch_bounds__(256, 2) void attn_kernel(
    const unsigned short* __restrict__ Qg,
    const unsigned short* __restrict__ Kg,
    const unsigned short* __restrict__ Vg,
    unsigned short* __restrict__ Opart,  // [wid32*split+s][8192] bf16
    float* __restrict__ ml,              // [wid32*split+s][64] (h-split partials)
    int split, int kb_base, int kb_rem)
{
  const int s     = blockIdx.x % split;
  const int stile = blockIdx.x / split;   // 0..195
  const int b     = stile / 98;
  const int qsup  = stile % 98;
  const int tid   = threadIdx.x;
  const int w     = tid >> 6;             // 0..3
  const int pr    = w >> 1;               // pair 0..1
  const int h     = w & 1;                // half within pair
  const int lane  = tid & 63;
  const int l15 = lane & 15, g = lane >> 4;
  const int wid32 = b * NT32 + qsup * 2 + pr;
  const int q0    = (qsup * 2 + pr) * 32;

  const int start = s * kb_base + (s < kb_rem ? s : kb_rem);
  const int cnt   = kb_base + (s < kb_rem ? 1 : 0);

  const unsigned short* Qb = Qg + (size_t)b * NN * CC;
  const unsigned short* Kb = Kg + (size_t)b * NN * CC;
  const unsigned short* Vb = Vg + (size_t)b * CC * NN;

  __shared__ __align__(16) unsigned short K_lds[2][32 * 256];  // 2 x 16 KB
  __shared__ __align__(16) unsigned short V_lds[2][256 * 32];  // 2 x 16 KB
  __shared__ __align__(16) unsigned short P_lds[2][32][40];    // per-pair P, 5 KB

  // ---- Q B-fragments for 32 queries pinned (64 VGPRs) ----------------
  s8v qf[2][8];
#pragma unroll
  for (int qt = 0; qt < 2; ++qt)
#pragma unroll
    for (int ks = 0; ks < 8; ++ks)
      qf[qt][ks] = *(const s8v*)(Qb + (size_t)(q0 + qt * 16 + l15) * CC + ks * 32 + g * 8);

  f4v ot[2][8];                            // [qt][mt]: channels h*128 + mt*16
  const f4v fz = {0.f, 0.f, 0.f, 0.f};
#pragma unroll
  for (int qt = 0; qt < 2; ++qt)
#pragma unroll
    for (int mt = 0; mt < 8; ++mt) ot[qt][mt] = fz;

  float lsum[2] = {0.f, 0.f};

  // ---- async stage of one 32-key tile (K waves 0-1, V waves 2-3) -----
  auto stage = [&](int buf, int kb32) {
    const int kb = kb32 * 32;
#pragma unroll
    for (int i = 0; i < 8; ++i) {
      int chunk = w * 512 + i * 64 + lane;             // 0..2047 (16B units)
      if (chunk < 1024) {                              // K part
        int r = chunk >> 5, cc = chunk & 31;
        const unsigned short* gp =
            Kb + (size_t)(kb + r) * CC + ((cc ^ (r & 15)) << 3);
        __builtin_amdgcn_global_load_lds(
            (const __attribute__((address_space(1))) unsigned int*)gp,
            (__attribute__((address_space(3))) unsigned int*)(&K_lds[buf][chunk * 8]),
            16, 0, 0);
      } else {                                         // V part
        int vc = chunk - 1024;
        int ch = vc >> 2, cc = vc & 3;
        const unsigned short* gp =
            Vb + (size_t)ch * NN + kb + ((cc ^ ((ch >> 1) & 3)) << 3);
        __builtin_amdgcn_global_load_lds(
            (const __attribute__((address_space(1))) unsigned int*)gp,
            (__attribute__((address_space(3))) unsigned int*)(&V_lds[buf][vc * 8]),
            16, 0, 0);
      }
    }
  };

  stage(0, start);
  int cur = 0;

  for (int ib = 0; ib < cnt; ++ib) {
    __syncthreads();                       // buf[cur] staged; prev P reads done
    if (ib + 1 < cnt) stage(cur ^ 1, start + ib + 1);   // prefetch next

    const unsigned short* Kl = &K_lds[cur][0];
    const unsigned short* Vl = &V_lds[cur][0];

    // ---- S^T = K[h-half] @ Q^T (16 keys x 32 queries; Q pre-scaled) --
    f4v st[2];
    st[0] = fz; st[1] = fz;
#pragma unroll
    for (int ks = 0; ks < 8; ++ks) {
      const int co = ((ks * 4 + g) ^ l15) << 3;        // swizzled 16B chunk
      s8v ka = *(const s8v*)(Kl + (h * 16 + l15) * 256 + co);
      st[0] = __builtin_amdgcn_mfma_f32_16x16x32_bf16(ka, qf[0][ks], st[0], 0, 0, 0);
      st[1] = __builtin_amdgcn_mfma_f32_16x16x32_bf16(ka, qf[1][ks], st[1], 0, 0, 0);
    }

    // ---- P = exp2(S), accumulate l, write pair-shared P slice --------
#pragma unroll
    for (int qt = 0; qt < 2; ++qt) {
      float p0 = __builtin_amdgcn_exp2f(st[qt][0]);
      float p1 = __builtin_amdgcn_exp2f(st[qt][1]);
      float p2 = __builtin_amdgcn_exp2f(st[qt][2]);
      float p3 = __builtin_amdgcn_exp2f(st[qt][3]);
      lsum[qt] += (p0 + p1) + (p2 + p3);
      ushort4 pk;
      pk.x = f2bf(p0); pk.y = f2bf(p1); pk.z = f2bf(p2); pk.w = f2bf(p3);
      *(ushort4*)(&P_lds[pr][qt * 16 + l15][h * 16 + g * 4]) = pk;
    }

    // ---- pair barrier: LDS-only wait, NO vmcnt drain (keeps prefetch)
    __builtin_amdgcn_sched_barrier(0);
    asm volatile("s_waitcnt lgkmcnt(0)" ::: "memory");
    __builtin_amdgcn_s_barrier();
    __builtin_amdgcn_sched_barrier(0);

    // ---- O^T += V^T[h-half channels] @ P^T (all 32 keys) -------------
    s8v pb0 = *(const s8v*)(&P_lds[pr][l15][g * 8]);
    s8v pb1 = *(const s8v*)(&P_lds[pr][16 + l15][g * 8]);
    const int vo = (g ^ ((l15 >> 1) & 3)) << 3;        // swizzled 16B chunk
#pragma unroll
    for (int mt = 0; mt < 8; ++mt) {
      s8v va = *(const s8v*)(Vl + (h * 128 + mt * 16 + l15) * 32 + vo);
      ot[0][mt] = __builtin_amdgcn_mfma_f32_16x16x32_bf16(va, pb0, ot[0][mt], 0, 0, 0);
      ot[1][mt] = __builtin_amdgcn_mfma_f32_16x16x32_bf16(va, pb1, ot[1][mt], 0, 0, 0);
    }

    cur ^= 1;
  }

  // ---- reduce l across the 4 g-groups (per key-half partials) --------
#pragma unroll
  for (int qt = 0; qt < 2; ++qt) {
    lsum[qt] += __shfl_xor(lsum[qt], 16);
    lsum[qt] += __shfl_xor(lsum[qt], 32);
  }

  // ---- nontemporal bf16 fragment-native partial dump -----------------
  unsigned short* Ob = Opart + (size_t)(wid32 * split + s) * 8192;
#pragma unroll
  for (int qt = 0; qt < 2; ++qt)
#pragma unroll
    for (int mt = 0; mt < 8; ++mt) {
      us4v o4;
      o4.x = f2bf(ot[qt][mt][0]); o4.y = f2bf(ot[qt][mt][1]);
      o4.z = f2bf(ot[qt][mt][2]); o4.w = f2bf(ot[qt][mt][3]);
      __builtin_nontemporal_store(
          o4, (us4v*)(Ob + qt * 4096 + (h * 8 + mt) * 256 + lane * 4));
    }

  if (lane < 16) {
    ml[(size_t)(wid32 * split + s) * 64 + h * 32 + lane]      = lsum[0];
    ml[(size_t)(wid32 * split + s) * 64 + h * 32 + 16 + lane] = lsum[1];
  }
}

// ---------------------------------------------------------------------------
// Merge: block = one 32-query tile (32 n x 256 c).
// Phase 1: read Opart fragment-native (dense 8B/lane), sum over splits,
//          normalize by L summed over split x key-half, deposit fp32 into
//          lds_o[c][n] (pad 33).
// Phase 2: fully-coalesced out = lds_o + x (128B line segments).
// ---------------------------------------------------------------------------
__global__ __launch_bounds__(256) void merge_kernel(
    const unsigned short* __restrict__ Opart,
    const float* __restrict__ ml,
    const float* __restrict__ x,
    float* __restrict__ out,
    int split)
{
  const int wid32 = blockIdx.x;             // 0..391
  const int b  = wid32 / NT32;
  const int pi = wid32 % NT32;
  const int n0 = pi * 32;
  const int tid = threadIdx.x;
  const int w = tid >> 6;
  const int lane = tid & 63;
  const int l15 = lane & 15, g = lane >> 4;

  __shared__ float lds_o[256][33];          // 33.8 KB

#pragma unroll
  for (int t = 0; t < 2; ++t) {
    float L = 0.f;
#pragma unroll
    for (int s = 0; s < 8; ++s)
      if (s < split) {
        L += ml[(size_t)(wid32 * split + s) * 64 + t * 16 + l15];
        L += ml[(size_t)(wid32 * split + s) * 64 + 32 + t * 16 + l15];
      }
    const float invL = 1.f / L;

#pragma unroll
    for (int j = 0; j < 4; ++j) {
      int mt = j * 4 + w;
      float a0 = 0.f, a1 = 0.f, a2 = 0.f, a3 = 0.f;
#pragma unroll
      for (int s = 0; s < 8; ++s)
        if (s < split) {
          const us4v* Op4 = (const us4v*)(Opart +
              (size_t)(wid32 * split + s) * 8192 + t * 4096);
          us4v o4 = __builtin_nontemporal_load(Op4 + mt * 64 + lane);
          a0 += bf2f(o4.x); a1 += bf2f(o4.y);
          a2 += bf2f(o4.z); a3 += bf2f(o4.w);
        }
      int c = mt * 16 + g * 4;
      int nl = t * 16 + l15;
      lds_o[c + 0][nl] = a0 * invL;
      lds_o[c + 1][nl] = a1 * invL;
      lds_o[c + 2][nl] = a2 * invL;
      lds_o[c + 3][nl] = a3 * invL;
    }
  }
  __syncthreads();

  const size_t base = (size_t)b * CC * NN + n0;
  const int n = tid & 31;
  const int c0 = tid >> 5;                  // 0..7
#pragma unroll
  for (int cg = 0; cg < 32; ++cg) {
    int c = cg * 8 + c0;
    size_t idx = base + (size_t)c * NN + n;
    out[idx] = lds_o[c][n] + x[idx];
  }
}

extern "C" void kernel_launch(void* const* d_in, const int* in_sizes, int n_in,
                              void* d_out, int out_size, void* d_ws, size_t ws_size,
                              hipStream_t stream) {
  const float* x   = (const float*)d_in[0];
  const float* ctx = (const float*)d_in[1];
  const float* wq  = (const float*)d_in[2];
  const float* bq  = (const float*)d_in[3];
  const float* wk  = (const float*)d_in[4];
  const float* bk  = (const float*)d_in[5];
  const float* wv  = (const float*)d_in[6];
  const float* bv  = (const float*)d_in[7];
  float* out = (float*)d_out;

  const size_t sz = (size_t)BB * NN * CC;
  unsigned short* Wb = (unsigned short*)d_ws;        // 384 KB
  unsigned short* Q  = Wb + 3 * 65536;
  unsigned short* K  = Q + sz;
  unsigned short* V  = K + sz;
  const size_t fixedB = 3 * 65536 * 2 + 3 * sz * 2;  // 19.66 MB

  int split = 1;
  const int cands[3] = {5, 2, 1};
  for (int i = 0; i < 3; ++i) {
    size_t need = fixedB + (size_t)cands[i] * (BB * NT32) *
                  (8192 * sizeof(unsigned short) + 64 * sizeof(float));
    if (ws_size >= need) { split = cands[i]; break; }
  }
  unsigned short* Opart = (unsigned short*)((char*)d_ws + fixedB);
  float* ml = (float*)(Opart + (size_t)split * (BB * NT32) * 8192);
  const int kb_base = NKB32 / split, kb_rem = NKB32 % split;

  wcvt_kernel<<<dim3(192), dim3(256), 0, stream>>>(wq, wk, wv, Wb);
  proj_kernel<<<dim3(NN / 32, BB, 3), dim3(256), 0, stream>>>(
      x, ctx, Wb, bq, bk, bv, Q, K, V);
  attn_kernel<<<dim3(196 * split), dim3(256), 0, stream>>>(
      Q, K, V, Opart, ml, split, kb_base, kb_rem);
  merge_kernel<<<dim3(BB * NT32), dim3(256), 0, stream>>>(
      Opart, ml, x, out, split);
}

// Round 5
// 252.363 us; speedup vs baseline: 1.9675x; 1.0075x over previous
//
#include <hip/hip_runtime.h>
#include <hip/hip_bf16.h>
#include <math.h>

#define BB 2
#define CC 256
#define NN 6272      // 8*28*28
#define NT32 196     // 32-query tiles per batch
#define NKB32 196    // 32-key tiles per batch
#define SCL 0.09016844005f   // log2(e)/sqrt(256)  (folded into Q at projection)

typedef __attribute__((ext_vector_type(8))) short s8v;   // 8 bf16 (4 VGPRs)
typedef __attribute__((ext_vector_type(4))) float f4v;   // MFMA acc / 16B vec
typedef __attribute__((ext_vector_type(4))) unsigned short us4v;  // 4 bf16
typedef __attribute__((ext_vector_type(2))) unsigned int u2v;     // 2x packed bf16

__device__ inline unsigned short f2bf(float f) {
  unsigned u = __builtin_bit_cast(unsigned, f);
  u += 0x7fffu + ((u >> 16) & 1u);     // RNE
  return (unsigned short)(u >> 16);
}

__device__ inline float bf2f(unsigned short h) {
  unsigned u = (unsigned)h << 16;
  return __builtin_bit_cast(float, u);
}

// packed f32x2 -> bf16x2 (RNE), single VALU op (T12 recipe, HW-verified)
__device__ inline unsigned cvtpk(float lo, float hi) {
  unsigned r;
  asm("v_cvt_pk_bf16_f32 %0, %1, %2" : "=v"(r) : "v"(lo), "v"(hi));
  return r;
}

// ---------------------------------------------------------------------------
// fp32 weights -> bf16 (once per launch)
// ---------------------------------------------------------------------------
__global__ __launch_bounds__(256) void wcvt_kernel(
    const float* __restrict__ wq, const float* __restrict__ wk,
    const float* __restrict__ wv, unsigned short* __restrict__ Wb)
{
  int i = (blockIdx.x * 256 + threadIdx.x) * 4;   // grid 192 -> i < 196608
  const float* src = (i < 65536) ? wq : (i < 131072 ? wk : wv);
  int off = i & 65535;
  float4 v = *(const float4*)(src + off);
  ushort4 o;
  o.x = f2bf(v.x); o.y = f2bf(v.y); o.z = f2bf(v.z); o.w = f2bf(v.w);
  *(ushort4*)(Wb + i) = o;
}

// ---------------------------------------------------------------------------
// MFMA projection
// p=0: Q*SCL -> [B][N][C]   p=1: K -> [B][N][C]   p=2: V -> [B][C][N]
// ---------------------------------------------------------------------------
__global__ __launch_bounds__(256) void proj_kernel(
    const float* __restrict__ x, const float* __restrict__ ctx,
    const unsigned short* __restrict__ Wb,
    const float* __restrict__ bq, const float* __restrict__ bk,
    const float* __restrict__ bv,
    unsigned short* __restrict__ Q, unsigned short* __restrict__ Kk,
    unsigned short* __restrict__ V)
{
  const int p = blockIdx.z, b = blockIdx.y;
  const int n0 = blockIdx.x * 32;
  const int tid = threadIdx.x;
  const float* in = (p == 0 ? x : ctx) + (size_t)b * CC * NN;
  const unsigned short* W = Wb + (size_t)p * 65536;
  const float* bias = (p == 0 ? bq : (p == 1 ? bk : bv));

  __shared__ __align__(16) unsigned short lds[32][264];   // [n][c]
  for (int it = tid; it < 2048; it += 256) {
    int c  = it >> 3;
    int n4 = (it & 7) << 2;
    float4 v = *(const float4*)(in + (size_t)c * NN + n0 + n4);
    lds[n4 + 0][c] = f2bf(v.x);
    lds[n4 + 1][c] = f2bf(v.y);
    lds[n4 + 2][c] = f2bf(v.z);
    lds[n4 + 3][c] = f2bf(v.w);
  }
  __syncthreads();

  const int lane = tid & 63, l15 = lane & 15, g = lane >> 4;
  const int obase = (tid >> 6) * 64;

  f4v acc[4][2];
#pragma unroll
  for (int mt = 0; mt < 4; ++mt) {
    float4 b4 = *(const float4*)(bias + obase + mt * 16 + g * 4);
    f4v bi = {b4.x, b4.y, b4.z, b4.w};
    acc[mt][0] = bi; acc[mt][1] = bi;
  }

#pragma unroll
  for (int ks = 0; ks < 8; ++ks) {
    s8v bf0 = *(const s8v*)(&lds[l15][ks * 32 + g * 8]);
    s8v bf1 = *(const s8v*)(&lds[16 + l15][ks * 32 + g * 8]);
#pragma unroll
    for (int mt = 0; mt < 4; ++mt) {
      s8v wa = *(const s8v*)(W + (size_t)(obase + mt * 16 + l15) * CC + ks * 32 + g * 8);
      acc[mt][0] = __builtin_amdgcn_mfma_f32_16x16x32_bf16(wa, bf0, acc[mt][0], 0, 0, 0);
      acc[mt][1] = __builtin_amdgcn_mfma_f32_16x16x32_bf16(wa, bf1, acc[mt][1], 0, 0, 0);
    }
  }

  if (p == 0) {
#pragma unroll
    for (int mt = 0; mt < 4; ++mt)
#pragma unroll
      for (int qq = 0; qq < 2; ++qq)
#pragma unroll
        for (int r = 0; r < 4; ++r)
          acc[mt][qq][r] *= SCL;
  }

  if (p < 2) {
    unsigned short* dst = (p == 0 ? Q : Kk) + (size_t)b * NN * CC;
#pragma unroll
    for (int mt = 0; mt < 4; ++mt)
#pragma unroll
      for (int qq = 0; qq < 2; ++qq) {
        u2v pk = {cvtpk(acc[mt][qq][0], acc[mt][qq][1]),
                  cvtpk(acc[mt][qq][2], acc[mt][qq][3])};
        *(u2v*)(dst + (size_t)(n0 + qq * 16 + l15) * CC + obase + mt * 16 + g * 4) = pk;
      }
  } else {
    unsigned short* dstb = V + (size_t)b * CC * NN;
#pragma unroll
    for (int mt = 0; mt < 4; ++mt)
#pragma unroll
      for (int qq = 0; qq < 2; ++qq)
#pragma unroll
        for (int r = 0; r < 4; ++r)
          dstb[(size_t)(obase + mt * 16 + g * 4 + r) * NN + n0 + qq * 16 + l15] =
              f2bf(acc[mt][qq][r]);
  }
}

// ---------------------------------------------------------------------------
// Flash attention (no-max exp2), wave-pair split. v5 = round-3 VERIFIED
// structure verbatim (incl. its staging — the round-4 incremental-offset
// staging rewrite NaN'd and is reverted wholesale), plus two provably-safe
// additions: (a) s_setprio(1/0) around the MFMA clusters (T5, hint only);
// (b) v_cvt_pk_bf16_f32 for the P pack / Opart dump / proj store (finite-in
// -> finite-out, cannot synthesize NaN).
// Pair split: 4 waves = 2 pairs; pair owns 32 q. Wave h: QK on keys
// h*16..+15 (8 K-frag reads), P exchange via per-pair LDS + lgkmcnt-only
// s_barrier (staging prefetch survives), PV on channels h*128..+127.
// ---------------------------------------------------------------------------
__global__ __launch_bounds__(256, 2) void attn_kernel(
    const unsigned short* __restrict__ Qg,
    const unsigned short* __restrict__ Kg,
    const unsigned short* __restrict__ Vg,
    unsigned short* __restrict__ Opart,  // [wid32*split+s][8192] bf16
    float* __restrict__ ml,              // [wid32*split+s][64] (h-split partials)
    int split, int kb_base, int kb_rem)
{
  const int s     = blockIdx.x % split;
  const int stile = blockIdx.x / split;   // 0..195
  const int b     = stile / 98;
  const int qsup  = stile % 98;
  const int tid   = threadIdx.x;
  const int w     = tid >> 6;             // 0..3
  const int pr    = w >> 1;               // pair 0..1
  const int h     = w & 1;                // half within pair
  const int lane  = tid & 63;
  const int l15 = lane & 15, g = lane >> 4;
  const int wid32 = b * NT32 + qsup * 2 + pr;
  const int q0    = (qsup * 2 + pr) * 32;

  const int start = s * kb_base + (s < kb_rem ? s : kb_rem);
  const int cnt   = kb_base + (s < kb_rem ? 1 : 0);

  const unsigned short* Qb = Qg + (size_t)b * NN * CC;
  const unsigned short* Kb = Kg + (size_t)b * NN * CC;
  const unsigned short* Vb = Vg + (size_t)b * CC * NN;

  __shared__ __align__(16) unsigned short K_lds[2][32 * 256];  // 2 x 16 KB
  __shared__ __align__(16) unsigned short V_lds[2][256 * 32];  // 2 x 16 KB
  __shared__ __align__(16) unsigned short P_lds[2][32][40];    // per-pair P, 5 KB

  // ---- Q B-fragments for 32 queries pinned (64 VGPRs) ----------------
  s8v qf[2][8];
#pragma unroll
  for (int qt = 0; qt < 2; ++qt)
#pragma unroll
    for (int ks = 0; ks < 8; ++ks)
      qf[qt][ks] = *(const s8v*)(Qb + (size_t)(q0 + qt * 16 + l15) * CC + ks * 32 + g * 8);

  f4v ot[2][8];                            // [qt][mt]: channels h*128 + mt*16
  const f4v fz = {0.f, 0.f, 0.f, 0.f};
#pragma unroll
  for (int qt = 0; qt < 2; ++qt)
#pragma unroll
    for (int mt = 0; mt < 8; ++mt) ot[qt][mt] = fz;

  float lsum[2] = {0.f, 0.f};

  // ---- async stage of one 32-key tile (K waves 0-1, V waves 2-3) -----
  // (round-3 verified form: per-call address computation, two call sites)
  auto stage = [&](int buf, int kb32) {
    const int kb = kb32 * 32;
#pragma unroll
    for (int i = 0; i < 8; ++i) {
      int chunk = w * 512 + i * 64 + lane;             // 0..2047 (16B units)
      if (chunk < 1024) {                              // K part
        int r = chunk >> 5, cc = chunk & 31;
        const unsigned short* gp =
            Kb + (size_t)(kb + r) * CC + ((cc ^ (r & 15)) << 3);
        __builtin_amdgcn_global_load_lds(
            (const __attribute__((address_space(1))) unsigned int*)gp,
            (__attribute__((address_space(3))) unsigned int*)(&K_lds[buf][chunk * 8]),
            16, 0, 0);
      } else {                                         // V part
        int vc = chunk - 1024;
        int ch = vc >> 2, cc = vc & 3;
        const unsigned short* gp =
            Vb + (size_t)ch * NN + kb + ((cc ^ ((ch >> 1) & 3)) << 3);
        __builtin_amdgcn_global_load_lds(
            (const __attribute__((address_space(1))) unsigned int*)gp,
            (__attribute__((address_space(3))) unsigned int*)(&V_lds[buf][vc * 8]),
            16, 0, 0);
      }
    }
  };

  stage(0, start);
  int cur = 0;

  for (int ib = 0; ib < cnt; ++ib) {
    __syncthreads();                       // buf[cur] staged; prev P reads done
    if (ib + 1 < cnt) stage(cur ^ 1, start + ib + 1);   // prefetch next

    const unsigned short* Kl = &K_lds[cur][0];
    const unsigned short* Vl = &V_lds[cur][0];

    // ---- S^T = K[h-half] @ Q^T (16 keys x 32 queries; Q pre-scaled) --
    f4v st[2];
    st[0] = fz; st[1] = fz;
    __builtin_amdgcn_s_setprio(1);
#pragma unroll
    for (int ks = 0; ks < 8; ++ks) {
      const int co = ((ks * 4 + g) ^ l15) << 3;        // swizzled 16B chunk
      s8v ka = *(const s8v*)(Kl + (h * 16 + l15) * 256 + co);
      st[0] = __builtin_amdgcn_mfma_f32_16x16x32_bf16(ka, qf[0][ks], st[0], 0, 0, 0);
      st[1] = __builtin_amdgcn_mfma_f32_16x16x32_bf16(ka, qf[1][ks], st[1], 0, 0, 0);
    }
    __builtin_amdgcn_s_setprio(0);

    // ---- P = exp2(S), accumulate l, write pair-shared P slice --------
#pragma unroll
    for (int qt = 0; qt < 2; ++qt) {
      float p0 = __builtin_amdgcn_exp2f(st[qt][0]);
      float p1 = __builtin_amdgcn_exp2f(st[qt][1]);
      float p2 = __builtin_amdgcn_exp2f(st[qt][2]);
      float p3 = __builtin_amdgcn_exp2f(st[qt][3]);
      lsum[qt] += (p0 + p1) + (p2 + p3);
      u2v pk = {cvtpk(p0, p1), cvtpk(p2, p3)};
      *(u2v*)(&P_lds[pr][qt * 16 + l15][h * 16 + g * 4]) = pk;
    }

    // ---- pair barrier: LDS-only wait, NO vmcnt drain (keeps prefetch)
    __builtin_amdgcn_sched_barrier(0);
    asm volatile("s_waitcnt lgkmcnt(0)" ::: "memory");
    __builtin_amdgcn_s_barrier();
    __builtin_amdgcn_sched_barrier(0);

    // ---- O^T += V^T[h-half channels] @ P^T (all 32 keys) -------------
    s8v pb0 = *(const s8v*)(&P_lds[pr][l15][g * 8]);
    s8v pb1 = *(const s8v*)(&P_lds[pr][16 + l15][g * 8]);
    const int vo = (g ^ ((l15 >> 1) & 3)) << 3;        // swizzled 16B chunk
    __builtin_amdgcn_s_setprio(1);
#pragma unroll
    for (int mt = 0; mt < 8; ++mt) {
      s8v va = *(const s8v*)(Vl + (h * 128 + mt * 16 + l15) * 32 + vo);
      ot[0][mt] = __builtin_amdgcn_mfma_f32_16x16x32_bf16(va, pb0, ot[0][mt], 0, 0, 0);
      ot[1][mt] = __builtin_amdgcn_mfma_f32_16x16x32_bf16(va, pb1, ot[1][mt], 0, 0, 0);
    }
    __builtin_amdgcn_s_setprio(0);

    cur ^= 1;
  }

  // ---- reduce l across the 4 g-groups (per key-half partials) --------
#pragma unroll
  for (int qt = 0; qt < 2; ++qt) {
    lsum[qt] += __shfl_xor(lsum[qt], 16);
    lsum[qt] += __shfl_xor(lsum[qt], 32);
  }

  // ---- nontemporal bf16 fragment-native partial dump -----------------
  unsigned short* Ob = Opart + (size_t)(wid32 * split + s) * 8192;
#pragma unroll
  for (int qt = 0; qt < 2; ++qt)
#pragma unroll
    for (int mt = 0; mt < 8; ++mt) {
      u2v o2 = {cvtpk(ot[qt][mt][0], ot[qt][mt][1]),
                cvtpk(ot[qt][mt][2], ot[qt][mt][3])};
      __builtin_nontemporal_store(
          o2, (u2v*)(Ob + qt * 4096 + (h * 8 + mt) * 256 + lane * 4));
    }

  if (lane < 16) {
    ml[(size_t)(wid32 * split + s) * 64 + h * 32 + lane]      = lsum[0];
    ml[(size_t)(wid32 * split + s) * 64 + h * 32 + 16 + lane] = lsum[1];
  }
}

// ---------------------------------------------------------------------------
// Merge: block = one 32-query tile (32 n x 256 c).
// Phase 1: read Opart fragment-native (dense 8B/lane), sum over splits,
//          normalize by L summed over split x key-half, deposit fp32 into
//          lds_o[c][n] (pad 33).
// Phase 2: fully-coalesced out = lds_o + x (128B line segments).
// ---------------------------------------------------------------------------
__global__ __launch_bounds__(256) void merge_kernel(
    const unsigned short* __restrict__ Opart,
    const float* __restrict__ ml,
    const float* __restrict__ x,
    float* __restrict__ out,
    int split)
{
  const int wid32 = blockIdx.x;             // 0..391
  const int b  = wid32 / NT32;
  const int pi = wid32 % NT32;
  const int n0 = pi * 32;
  const int tid = threadIdx.x;
  const int w = tid >> 6;
  const int lane = tid & 63;
  const int l15 = lane & 15, g = lane >> 4;

  __shared__ float lds_o[256][33];          // 33.8 KB

#pragma unroll
  for (int t = 0; t < 2; ++t) {
    float L = 0.f;
#pragma unroll
    for (int s = 0; s < 8; ++s)
      if (s < split) {
        L += ml[(size_t)(wid32 * split + s) * 64 + t * 16 + l15];
        L += ml[(size_t)(wid32 * split + s) * 64 + 32 + t * 16 + l15];
      }
    const float invL = 1.f / L;

#pragma unroll
    for (int j = 0; j < 4; ++j) {
      int mt = j * 4 + w;
      float a0 = 0.f, a1 = 0.f, a2 = 0.f, a3 = 0.f;
#pragma unroll
      for (int s = 0; s < 8; ++s)
        if (s < split) {
          const us4v* Op4 = (const us4v*)(Opart +
              (size_t)(wid32 * split + s) * 8192 + t * 4096);
          us4v o4 = __builtin_nontemporal_load(Op4 + mt * 64 + lane);
          a0 += bf2f(o4.x); a1 += bf2f(o4.y);
          a2 += bf2f(o4.z); a3 += bf2f(o4.w);
        }
      int c = mt * 16 + g * 4;
      int nl = t * 16 + l15;
      lds_o[c + 0][nl] = a0 * invL;
      lds_o[c + 1][nl] = a1 * invL;
      lds_o[c + 2][nl] = a2 * invL;
      lds_o[c + 3][nl] = a3 * invL;
    }
  }
  __syncthreads();

  const size_t base = (size_t)b * CC * NN + n0;
  const int n = tid & 31;
  const int c0 = tid >> 5;                  // 0..7
#pragma unroll
  for (int cg = 0; cg < 32; ++cg) {
    int c = cg * 8 + c0;
    size_t idx = base + (size_t)c * NN + n;
    out[idx] = lds_o[c][n] + x[idx];
  }
}

extern "C" void kernel_launch(void* const* d_in, const int* in_sizes, int n_in,
                              void* d_out, int out_size, void* d_ws, size_t ws_size,
                              hipStream_t stream) {
  const float* x   = (const float*)d_in[0];
  const float* ctx = (const float*)d_in[1];
  const float* wq  = (const float*)d_in[2];
  const float* bq  = (const float*)d_in[3];
  const float* wk  = (const float*)d_in[4];
  const float* bk  = (const float*)d_in[5];
  const float* wv  = (const float*)d_in[6];
  const float* bv  = (const float*)d_in[7];
  float* out = (float*)d_out;

  const size_t sz = (size_t)BB * NN * CC;
  unsigned short* Wb = (unsigned short*)d_ws;        // 384 KB
  unsigned short* Q  = Wb + 3 * 65536;
  unsigned short* K  = Q + sz;
  unsigned short* V  = K + sz;
  const size_t fixedB = 3 * 65536 * 2 + 3 * sz * 2;  // 19.66 MB

  int split = 1;
  const int cands[3] = {5, 2, 1};
  for (int i = 0; i < 3; ++i) {
    size_t need = fixedB + (size_t)cands[i] * (BB * NT32) *
                  (8192 * sizeof(unsigned short) + 64 * sizeof(float));
    if (ws_size >= need) { split = cands[i]; break; }
  }
  unsigned short* Opart = (unsigned short*)((char*)d_ws + fixedB);
  float* ml = (float*)(Opart + (size_t)split * (BB * NT32) * 8192);
  const int kb_base = NKB32 / split, kb_rem = NKB32 % split;

  wcvt_kernel<<<dim3(192), dim3(256), 0, stream>>>(wq, wk, wv, Wb);
  proj_kernel<<<dim3(NN / 32, BB, 3), dim3(256), 0, stream>>>(
      x, ctx, Wb, bq, bk, bv, Q, K, V);
  attn_kernel<<<dim3(196 * split), dim3(256), 0, stream>>>(
      Q, K, V, Opart, ml, split, kb_base, kb_rem);
  merge_kernel<<<dim3(BB * NT32), dim3(256), 0, stream>>>(
      Opart, ml, x, out, split);
}

// Round 6
// 235.840 us; speedup vs baseline: 2.1054x; 1.0701x over previous
//
#include <hip/hip_runtime.h>
#include <hip/hip_bf16.h>
#include <math.h>

#define BB 2
#define CC 256
#define NN 6272      // 8*28*28
#define NT32 196     // 32-query tiles per batch
#define NKB32 196    // 32-key tiles per batch
#define SCL 0.09016844005f   // log2(e)/sqrt(256)  (folded into Q at projection)

typedef __attribute__((ext_vector_type(8))) short s8v;   // 8 bf16 (4 VGPRs)
typedef __attribute__((ext_vector_type(4))) float f4v;   // MFMA acc / 16B vec
typedef __attribute__((ext_vector_type(4))) unsigned short us4v;  // 4 bf16
typedef __attribute__((ext_vector_type(2))) unsigned int u2v;     // 2x packed bf16

__device__ inline unsigned short f2bf(float f) {
  unsigned u = __builtin_bit_cast(unsigned, f);
  u += 0x7fffu + ((u >> 16) & 1u);     // RNE
  return (unsigned short)(u >> 16);
}

__device__ inline float bf2f(unsigned short h) {
  unsigned u = (unsigned)h << 16;
  return __builtin_bit_cast(float, u);
}

// packed f32x2 -> bf16x2 (RNE), single VALU op (T12 recipe, HW-verified)
__device__ inline unsigned cvtpk(float lo, float hi) {
  unsigned r;
  asm("v_cvt_pk_bf16_f32 %0, %1, %2" : "=v"(r) : "v"(lo), "v"(hi));
  return r;
}

// ---------------------------------------------------------------------------
// fp32 weights -> bf16 (once per launch)
// ---------------------------------------------------------------------------
__global__ __launch_bounds__(256) void wcvt_kernel(
    const float* __restrict__ wq, const float* __restrict__ wk,
    const float* __restrict__ wv, unsigned short* __restrict__ Wb)
{
  int i = (blockIdx.x * 256 + threadIdx.x) * 4;   // grid 192 -> i < 196608
  const float* src = (i < 65536) ? wq : (i < 131072 ? wk : wv);
  int off = i & 65535;
  float4 v = *(const float4*)(src + off);
  ushort4 o;
  o.x = f2bf(v.x); o.y = f2bf(v.y); o.z = f2bf(v.z); o.w = f2bf(v.w);
  *(ushort4*)(Wb + i) = o;
}

// ---------------------------------------------------------------------------
// MFMA projection
// p=0: Q*SCL -> [B][N][C]   p=1: K -> [B][N][C]   p=2: V -> [B][C][N]
// ---------------------------------------------------------------------------
__global__ __launch_bounds__(256) void proj_kernel(
    const float* __restrict__ x, const float* __restrict__ ctx,
    const unsigned short* __restrict__ Wb,
    const float* __restrict__ bq, const float* __restrict__ bk,
    const float* __restrict__ bv,
    unsigned short* __restrict__ Q, unsigned short* __restrict__ Kk,
    unsigned short* __restrict__ V)
{
  const int p = blockIdx.z, b = blockIdx.y;
  const int n0 = blockIdx.x * 32;
  const int tid = threadIdx.x;
  const float* in = (p == 0 ? x : ctx) + (size_t)b * CC * NN;
  const unsigned short* W = Wb + (size_t)p * 65536;
  const float* bias = (p == 0 ? bq : (p == 1 ? bk : bv));

  __shared__ __align__(16) unsigned short lds[32][264];   // [n][c]
  for (int it = tid; it < 2048; it += 256) {
    int c  = it >> 3;
    int n4 = (it & 7) << 2;
    float4 v = *(const float4*)(in + (size_t)c * NN + n0 + n4);
    lds[n4 + 0][c] = f2bf(v.x);
    lds[n4 + 1][c] = f2bf(v.y);
    lds[n4 + 2][c] = f2bf(v.z);
    lds[n4 + 3][c] = f2bf(v.w);
  }
  __syncthreads();

  const int lane = tid & 63, l15 = lane & 15, g = lane >> 4;
  const int obase = (tid >> 6) * 64;

  f4v acc[4][2];
#pragma unroll
  for (int mt = 0; mt < 4; ++mt) {
    float4 b4 = *(const float4*)(bias + obase + mt * 16 + g * 4);
    f4v bi = {b4.x, b4.y, b4.z, b4.w};
    acc[mt][0] = bi; acc[mt][1] = bi;
  }

#pragma unroll
  for (int ks = 0; ks < 8; ++ks) {
    s8v bf0 = *(const s8v*)(&lds[l15][ks * 32 + g * 8]);
    s8v bf1 = *(const s8v*)(&lds[16 + l15][ks * 32 + g * 8]);
#pragma unroll
    for (int mt = 0; mt < 4; ++mt) {
      s8v wa = *(const s8v*)(W + (size_t)(obase + mt * 16 + l15) * CC + ks * 32 + g * 8);
      acc[mt][0] = __builtin_amdgcn_mfma_f32_16x16x32_bf16(wa, bf0, acc[mt][0], 0, 0, 0);
      acc[mt][1] = __builtin_amdgcn_mfma_f32_16x16x32_bf16(wa, bf1, acc[mt][1], 0, 0, 0);
    }
  }

  if (p == 0) {
#pragma unroll
    for (int mt = 0; mt < 4; ++mt)
#pragma unroll
      for (int qq = 0; qq < 2; ++qq)
#pragma unroll
        for (int r = 0; r < 4; ++r)
          acc[mt][qq][r] *= SCL;
  }

  if (p < 2) {
    unsigned short* dst = (p == 0 ? Q : Kk) + (size_t)b * NN * CC;
#pragma unroll
    for (int mt = 0; mt < 4; ++mt)
#pragma unroll
      for (int qq = 0; qq < 2; ++qq) {
        u2v pk = {cvtpk(acc[mt][qq][0], acc[mt][qq][1]),
                  cvtpk(acc[mt][qq][2], acc[mt][qq][3])};
        *(u2v*)(dst + (size_t)(n0 + qq * 16 + l15) * CC + obase + mt * 16 + g * 4) = pk;
      }
  } else {
    unsigned short* dstb = V + (size_t)b * CC * NN;
#pragma unroll
    for (int mt = 0; mt < 4; ++mt)
#pragma unroll
      for (int qq = 0; qq < 2; ++qq)
#pragma unroll
        for (int r = 0; r < 4; ++r)
          dstb[(size_t)(obase + mt * 16 + g * 4 + r) * NN + n0 + qq * 16 + l15] =
              f2bf(acc[mt][qq][r]);
  }
}

// ---------------------------------------------------------------------------
// Flash attention (no-max exp2), wave-pair split. v6 = r5 (verified) +
// (a) PV V-fragment PRELOAD: the 8 va ds_reads depend only on V_lds[cur]
//     (staged last iter, stable all tile) -- issue them during the SM phase,
//     BEFORE the pair barrier, into 32 VGPRs; the existing lgkmcnt(0) +
//     s_barrier covers them. Removes ~8x ds-latency serialization in front
//     of the PV MFMAs each tile.
// (b) staging-address hoist (value-identical refactor of r5's arithmetic):
//     per-lane invariant byte offsets offs[8] computed once; stage keeps the
//     exact r5 two-branch body + static LDS expressions; global address is
//     base + kb32*stride + offs[i]  (stride: K 8192 shorts, V 32 shorts).
// ---------------------------------------------------------------------------
__global__ __launch_bounds__(256, 2) void attn_kernel(
    const unsigned short* __restrict__ Qg,
    const unsigned short* __restrict__ Kg,
    const unsigned short* __restrict__ Vg,
    unsigned short* __restrict__ Opart,  // [wid32*split+s][8192] bf16
    float* __restrict__ ml,              // [wid32*split+s][64] (h-split partials)
    int split, int kb_base, int kb_rem)
{
  const int s     = blockIdx.x % split;
  const int stile = blockIdx.x / split;   // 0..195
  const int b     = stile / 98;
  const int qsup  = stile % 98;
  const int tid   = threadIdx.x;
  const int w     = tid >> 6;             // 0..3
  const int pr    = w >> 1;               // pair 0..1
  const int h     = w & 1;                // half within pair
  const int lane  = tid & 63;
  const int l15 = lane & 15, g = lane >> 4;
  const int wid32 = b * NT32 + qsup * 2 + pr;
  const int q0    = (qsup * 2 + pr) * 32;

  const int start = s * kb_base + (s < kb_rem ? s : kb_rem);
  const int cnt   = kb_base + (s < kb_rem ? 1 : 0);

  const unsigned short* Qb = Qg + (size_t)b * NN * CC;
  const unsigned short* Kb = Kg + (size_t)b * NN * CC;
  const unsigned short* Vb = Vg + (size_t)b * CC * NN;

  __shared__ __align__(16) unsigned short K_lds[2][32 * 256];  // 2 x 16 KB
  __shared__ __align__(16) unsigned short V_lds[2][256 * 32];  // 2 x 16 KB
  __shared__ __align__(16) unsigned short P_lds[2][32][40];    // per-pair P, 5 KB

  // ---- per-lane invariant staging offsets (shorts) -------------------
  int offs[8];
#pragma unroll
  for (int i = 0; i < 8; ++i) {
    const int chunk = w * 512 + i * 64 + lane;       // 0..2047 (16B units)
    if (chunk < 1024) {                              // K part
      const int r = chunk >> 5, cc = chunk & 31;
      offs[i] = r * CC + ((cc ^ (r & 15)) << 3);
    } else {                                         // V part
      const int vc = chunk - 1024;
      const int ch = vc >> 2, c3 = vc & 3;
      offs[i] = ch * NN + ((c3 ^ ((ch >> 1) & 3)) << 3);
    }
  }

  // ---- Q B-fragments for 32 queries pinned (64 VGPRs) ----------------
  s8v qf[2][8];
#pragma unroll
  for (int qt = 0; qt < 2; ++qt)
#pragma unroll
    for (int ks = 0; ks < 8; ++ks)
      qf[qt][ks] = *(const s8v*)(Qb + (size_t)(q0 + qt * 16 + l15) * CC + ks * 32 + g * 8);

  f4v ot[2][8];                            // [qt][mt]: channels h*128 + mt*16
  const f4v fz = {0.f, 0.f, 0.f, 0.f};
#pragma unroll
  for (int qt = 0; qt < 2; ++qt)
#pragma unroll
    for (int mt = 0; mt < 8; ++mt) ot[qt][mt] = fz;

  float lsum[2] = {0.f, 0.f};

  // ---- async stage of one 32-key tile (K waves 0-1, V waves 2-3) -----
  auto stage = [&](int buf, int kb32) {
#pragma unroll
    for (int i = 0; i < 8; ++i) {
      int chunk = w * 512 + i * 64 + lane;             // 0..2047 (16B units)
      if (chunk < 1024) {                              // K part
        const unsigned short* gp = Kb + (size_t)kb32 * 8192 + offs[i];
        __builtin_amdgcn_global_load_lds(
            (const __attribute__((address_space(1))) unsigned int*)gp,
            (__attribute__((address_space(3))) unsigned int*)(&K_lds[buf][chunk * 8]),
            16, 0, 0);
      } else {                                         // V part
        int vc = chunk - 1024;
        const unsigned short* gp = Vb + (size_t)kb32 * 32 + offs[i];
        __builtin_amdgcn_global_load_lds(
            (const __attribute__((address_space(1))) unsigned int*)gp,
            (__attribute__((address_space(3))) unsigned int*)(&V_lds[buf][vc * 8]),
            16, 0, 0);
      }
    }
  };

  stage(0, start);
  int cur = 0;

  for (int ib = 0; ib < cnt; ++ib) {
    __syncthreads();                       // buf[cur] staged; prev P reads done
    if (ib + 1 < cnt) stage(cur ^ 1, start + ib + 1);   // prefetch next

    const unsigned short* Kl = &K_lds[cur][0];
    const unsigned short* Vl = &V_lds[cur][0];

    // ---- S^T = K[h-half] @ Q^T (16 keys x 32 queries; Q pre-scaled) --
    f4v st[2];
    st[0] = fz; st[1] = fz;
    __builtin_amdgcn_s_setprio(1);
#pragma unroll
    for (int ks = 0; ks < 8; ++ks) {
      const int co = ((ks * 4 + g) ^ l15) << 3;        // swizzled 16B chunk
      s8v ka = *(const s8v*)(Kl + (h * 16 + l15) * 256 + co);
      st[0] = __builtin_amdgcn_mfma_f32_16x16x32_bf16(ka, qf[0][ks], st[0], 0, 0, 0);
      st[1] = __builtin_amdgcn_mfma_f32_16x16x32_bf16(ka, qf[1][ks], st[1], 0, 0, 0);
    }
    __builtin_amdgcn_s_setprio(0);

    // ---- PV V-fragment preload (depends only on V_lds[cur], stable) --
    const int vo = (g ^ ((l15 >> 1) & 3)) << 3;        // swizzled 16B chunk
    s8v va_[8];
#pragma unroll
    for (int mt = 0; mt < 8; ++mt)
      va_[mt] = *(const s8v*)(Vl + (h * 128 + mt * 16 + l15) * 32 + vo);

    // ---- P = exp2(S), accumulate l, write pair-shared P slice --------
#pragma unroll
    for (int qt = 0; qt < 2; ++qt) {
      float p0 = __builtin_amdgcn_exp2f(st[qt][0]);
      float p1 = __builtin_amdgcn_exp2f(st[qt][1]);
      float p2 = __builtin_amdgcn_exp2f(st[qt][2]);
      float p3 = __builtin_amdgcn_exp2f(st[qt][3]);
      lsum[qt] += (p0 + p1) + (p2 + p3);
      u2v pk = {cvtpk(p0, p1), cvtpk(p2, p3)};
      *(u2v*)(&P_lds[pr][qt * 16 + l15][h * 16 + g * 4]) = pk;
    }

    // ---- pair barrier: LDS-only wait, NO vmcnt drain (keeps prefetch)
    __builtin_amdgcn_sched_barrier(0);
    asm volatile("s_waitcnt lgkmcnt(0)" ::: "memory");
    __builtin_amdgcn_s_barrier();
    __builtin_amdgcn_sched_barrier(0);

    // ---- O^T += V^T[h-half channels] @ P^T (all 32 keys) -------------
    s8v pb0 = *(const s8v*)(&P_lds[pr][l15][g * 8]);
    s8v pb1 = *(const s8v*)(&P_lds[pr][16 + l15][g * 8]);
    __builtin_amdgcn_s_setprio(1);
#pragma unroll
    for (int mt = 0; mt < 8; ++mt) {
      ot[0][mt] = __builtin_amdgcn_mfma_f32_16x16x32_bf16(va_[mt], pb0, ot[0][mt], 0, 0, 0);
      ot[1][mt] = __builtin_amdgcn_mfma_f32_16x16x32_bf16(va_[mt], pb1, ot[1][mt], 0, 0, 0);
    }
    __builtin_amdgcn_s_setprio(0);

    cur ^= 1;
  }

  // ---- reduce l across the 4 g-groups (per key-half partials) --------
#pragma unroll
  for (int qt = 0; qt < 2; ++qt) {
    lsum[qt] += __shfl_xor(lsum[qt], 16);
    lsum[qt] += __shfl_xor(lsum[qt], 32);
  }

  // ---- nontemporal bf16 fragment-native partial dump -----------------
  unsigned short* Ob = Opart + (size_t)(wid32 * split + s) * 8192;
#pragma unroll
  for (int qt = 0; qt < 2; ++qt)
#pragma unroll
    for (int mt = 0; mt < 8; ++mt) {
      u2v o2 = {cvtpk(ot[qt][mt][0], ot[qt][mt][1]),
                cvtpk(ot[qt][mt][2], ot[qt][mt][3])};
      __builtin_nontemporal_store(
          o2, (u2v*)(Ob + qt * 4096 + (h * 8 + mt) * 256 + lane * 4));
    }

  if (lane < 16) {
    ml[(size_t)(wid32 * split + s) * 64 + h * 32 + lane]      = lsum[0];
    ml[(size_t)(wid32 * split + s) * 64 + h * 32 + 16 + lane] = lsum[1];
  }
}

// ---------------------------------------------------------------------------
// Merge: block = one 32-query tile (32 n x 256 c).
// Phase 1: read Opart fragment-native (dense 8B/lane), sum over splits,
//          normalize by L summed over split x key-half, deposit fp32 into
//          lds_o[c][n] (pad 33).
// Phase 2: fully-coalesced out = lds_o + x (128B line segments).
// ---------------------------------------------------------------------------
__global__ __launch_bounds__(256) void merge_kernel(
    const unsigned short* __restrict__ Opart,
    const float* __restrict__ ml,
    const float* __restrict__ x,
    float* __restrict__ out,
    int split)
{
  const int wid32 = blockIdx.x;             // 0..391
  const int b  = wid32 / NT32;
  const int pi = wid32 % NT32;
  const int n0 = pi * 32;
  const int tid = threadIdx.x;
  const int w = tid >> 6;
  const int lane = tid & 63;
  const int l15 = lane & 15, g = lane >> 4;

  __shared__ float lds_o[256][33];          // 33.8 KB

#pragma unroll
  for (int t = 0; t < 2; ++t) {
    float L = 0.f;
#pragma unroll
    for (int s = 0; s < 8; ++s)
      if (s < split) {
        L += ml[(size_t)(wid32 * split + s) * 64 + t * 16 + l15];
        L += ml[(size_t)(wid32 * split + s) * 64 + 32 + t * 16 + l15];
      }
    const float invL = 1.f / L;

#pragma unroll
    for (int j = 0; j < 4; ++j) {
      int mt = j * 4 + w;
      float a0 = 0.f, a1 = 0.f, a2 = 0.f, a3 = 0.f;
#pragma unroll
      for (int s = 0; s < 8; ++s)
        if (s < split) {
          const us4v* Op4 = (const us4v*)(Opart +
              (size_t)(wid32 * split + s) * 8192 + t * 4096);
          us4v o4 = __builtin_nontemporal_load(Op4 + mt * 64 + lane);
          a0 += bf2f(o4.x); a1 += bf2f(o4.y);
          a2 += bf2f(o4.z); a3 += bf2f(o4.w);
        }
      int c = mt * 16 + g * 4;
      int nl = t * 16 + l15;
      lds_o[c + 0][nl] = a0 * invL;
      lds_o[c + 1][nl] = a1 * invL;
      lds_o[c + 2][nl] = a2 * invL;
      lds_o[c + 3][nl] = a3 * invL;
    }
  }
  __syncthreads();

  const size_t base = (size_t)b * CC * NN + n0;
  const int n = tid & 31;
  const int c0 = tid >> 5;                  // 0..7
#pragma unroll
  for (int cg = 0; cg < 32; ++cg) {
    int c = cg * 8 + c0;
    size_t idx = base + (size_t)c * NN + n;
    out[idx] = lds_o[c][n] + x[idx];
  }
}

extern "C" void kernel_launch(void* const* d_in, const int* in_sizes, int n_in,
                              void* d_out, int out_size, void* d_ws, size_t ws_size,
                              hipStream_t stream) {
  const float* x   = (const float*)d_in[0];
  const float* ctx = (const float*)d_in[1];
  const float* wq  = (const float*)d_in[2];
  const float* bq  = (const float*)d_in[3];
  const float* wk  = (const float*)d_in[4];
  const float* bk  = (const float*)d_in[5];
  const float* wv  = (const float*)d_in[6];
  const float* bv  = (const float*)d_in[7];
  float* out = (float*)d_out;

  const size_t sz = (size_t)BB * NN * CC;
  unsigned short* Wb = (unsigned short*)d_ws;        // 384 KB
  unsigned short* Q  = Wb + 3 * 65536;
  unsigned short* K  = Q + sz;
  unsigned short* V  = K + sz;
  const size_t fixedB = 3 * 65536 * 2 + 3 * sz * 2;  // 19.66 MB

  int split = 1;
  const int cands[3] = {5, 2, 1};
  for (int i = 0; i < 3; ++i) {
    size_t need = fixedB + (size_t)cands[i] * (BB * NT32) *
                  (8192 * sizeof(unsigned short) + 64 * sizeof(float));
    if (ws_size >= need) { split = cands[i]; break; }
  }
  unsigned short* Opart = (unsigned short*)((char*)d_ws + fixedB);
  float* ml = (float*)(Opart + (size_t)split * (BB * NT32) * 8192);
  const int kb_base = NKB32 / split, kb_rem = NKB32 % split;

  wcvt_kernel<<<dim3(192), dim3(256), 0, stream>>>(wq, wk, wv, Wb);
  proj_kernel<<<dim3(NN / 32, BB, 3), dim3(256), 0, stream>>>(
      x, ctx, Wb, bq, bk, bv, Q, K, V);
  attn_kernel<<<dim3(196 * split), dim3(256), 0, stream>>>(
      Q, K, V, Opart, ml, split, kb_base, kb_rem);
  merge_kernel<<<dim3(BB * NT32), dim3(256), 0, stream>>>(
      Opart, ml, x, out, split);
}